// Round 5
// baseline (1089.196 us; speedup 1.0000x reference)
//
#include <hip/hip_runtime.h>

#define IN_F 256
#define HID  128
#define NCLS 40
#define MAXBKT 2048   // buckets of 64 nodes: supports N <= 131072

typedef __attribute__((ext_vector_type(8))) short bf16x8;
typedef __attribute__((ext_vector_type(4))) float f32x4;

static __device__ __forceinline__ unsigned short f2bf(float f) {
    unsigned u = __builtin_bit_cast(unsigned, f);
    u += 0x7fffu + ((u >> 16) & 1u);   // round-to-nearest-even
    return (unsigned short)(u >> 16);
}

// ---------------- zero ----------------
__global__ void zero4_kernel(float4* __restrict__ p, int n4) {
    int i = blockIdx.x * blockDim.x + threadIdx.x;
    if (i < n4) p[i] = make_float4(0.f, 0.f, 0.f, 0.f);
}

// ---------------- count: LDS bucket histogram + global out-degree ----------------
__global__ __launch_bounds__(256) void count_kernel(
    const int* __restrict__ src, const int* __restrict__ dst,
    int* __restrict__ cnt_out, int* __restrict__ bktCnt, int E) {
    __shared__ int hist[MAXBKT];
    for (int h = threadIdx.x; h < MAXBKT; h += 256) hist[h] = 0;
    __syncthreads();
    int stride = gridDim.x * 256;
    for (int i = blockIdx.x * 256 + threadIdx.x; i < E; i += stride) {
        atomicAdd(&cnt_out[src[i]], 1);
        atomicAdd(&hist[dst[i] >> 6], 1);
    }
    __syncthreads();
    for (int h = threadIdx.x; h < MAXBKT; h += 256) {
        int c = hist[h];
        if (c) atomicAdd(&bktCnt[h], c);
    }
}

// ---------------- bucket exclusive scan (one block, 2048 entries) ----------------
__global__ __launch_bounds__(1024) void bscan_kernel(const int* __restrict__ bktCnt,
                                                     int* __restrict__ bktBase,
                                                     int* __restrict__ bktCursor) {
    __shared__ int s[1024];
    int t = threadIdx.x;
    int a = bktCnt[2 * t], b = bktCnt[2 * t + 1];
    s[t] = a + b;
    __syncthreads();
    for (int off = 1; off < 1024; off <<= 1) {
        int v = (t >= off) ? s[t - off] : 0;
        __syncthreads();
        s[t] += v;
        __syncthreads();
    }
    int excl = s[t] - (a + b);
    bktBase[2 * t] = excl;       bktBase[2 * t + 1] = excl + a;
    bktCursor[2 * t] = excl;     bktCursor[2 * t + 1] = excl + a;
}

__global__ void rsout_kernel(const int* __restrict__ cnt_out, float* __restrict__ rs_out, int N) {
    int i = blockIdx.x * blockDim.x + threadIdx.x;
    if (i < N) rs_out[i] = rsqrtf((float)max(cnt_out[i], 1));
}

// ---------------- binA: append packed (dst&63, src) to bucket region ----------------
__global__ void binA_kernel(const int* __restrict__ src, const int* __restrict__ dst,
                            int* __restrict__ bktCursor, int* __restrict__ bin, int E) {
    int i = blockIdx.x * 256 + threadIdx.x;
    if (i < E) {
        int d = dst[i];
        int p = atomicAdd(&bktCursor[d >> 6], 1);
        bin[p] = ((d & 63) << 17) | src[i];
    }
}

// ---------------- passB: per-bucket LDS counting sort -> csr_src, row_ptr, rs_in --------
__global__ __launch_bounds__(256) void passB_kernel(
    const int* __restrict__ bktBase, const int* __restrict__ bin,
    int* __restrict__ csr_src, int* __restrict__ row_ptr, float* __restrict__ rs_in, int N) {
    __shared__ int cnt[64];
    __shared__ int cur[64];
    const int b = blockIdx.x;
    const int base = bktBase[b], end = bktBase[b + 1];
    const int tx = threadIdx.x;
    if (tx < 64) cnt[tx] = 0;
    __syncthreads();
    for (int i = base + tx; i < end; i += 256)
        atomicAdd(&cnt[bin[i] >> 17], 1);
    __syncthreads();
    if (tx < 64) {
        int excl = 0;
        for (int m = 0; m < tx; ++m) excl += cnt[m];
        cur[tx] = excl;
        int idx = b * 64 + tx;
        row_ptr[idx] = base + excl;                 // row_ptr sized N+64; idx<N+64 always
        if (idx < N) rs_in[idx] = rsqrtf((float)max(cnt[tx], 1));
    }
    __syncthreads();
    for (int i = base + tx; i < end; i += 256) {
        int v = bin[i];
        int p = atomicAdd(&cur[v >> 17], 1);
        csr_src[base + p] = v & 0x1FFFF;
    }
}

// ---------------- GEMM1 (MFMA bf16): h1b = bf16((x*rs_out) @ W1)  [N,256]@[256,128] ------
__global__ __launch_bounds__(256) void gemm1_kernel(
    const float* __restrict__ x, const float* __restrict__ W1,
    const float* __restrict__ rs_out, unsigned short* __restrict__ h1b, int N) {
    __shared__ unsigned short Wl[32768];  // 64 KB

    const int tx = threadIdx.x;
#pragma unroll
    for (int e = 0; e < 32; ++e) {
        int base = (tx + 256 * e) * 4;
        float4 w = *(const float4*)&W1[base];
        int k = base >> 7;
        int c0 = base & 127;
        float wv[4] = {w.x, w.y, w.z, w.w};
#pragma unroll
        for (int q = 0; q < 4; ++q) {
            int col = c0 + q;
            int byte = col * 512 + k * 2;
            byte ^= (col & 7) << 4;
            Wl[byte >> 1] = f2bf(wv[q]);
        }
    }
    __syncthreads();

    const int wv_ = tx >> 6, lane = tx & 63;
    const int r0 = blockIdx.x * 64 + wv_ * 16;
    const int arow = r0 + (lane & 15);
    const int arow_c = min(arow, N - 1);
    const float rs = rs_out[arow_c];
    const long xbase = (long)arow_c * IN_F + (lane >> 4) * 8;

    bf16x8 a8[8];
#pragma unroll
    for (int ks = 0; ks < 8; ++ks) {
        float4 p0 = *(const float4*)&x[xbase + ks * 32];
        float4 p1 = *(const float4*)&x[xbase + ks * 32 + 4];
        bf16x8 a;
        a[0] = (short)f2bf(p0.x * rs); a[1] = (short)f2bf(p0.y * rs);
        a[2] = (short)f2bf(p0.z * rs); a[3] = (short)f2bf(p0.w * rs);
        a[4] = (short)f2bf(p1.x * rs); a[5] = (short)f2bf(p1.y * rs);
        a[6] = (short)f2bf(p1.z * rs); a[7] = (short)f2bf(p1.w * rs);
        a8[ks] = a;
    }

    f32x4 acc[8];
#pragma unroll
    for (int nf = 0; nf < 8; ++nf) acc[nf] = (f32x4){0.f, 0.f, 0.f, 0.f};

#pragma unroll
    for (int ks = 0; ks < 8; ++ks) {
#pragma unroll
        for (int nf = 0; nf < 8; ++nf) {
            int col = nf * 16 + (lane & 15);
            int kb  = ks * 32 + (lane >> 4) * 8;
            int byte = col * 512 + kb * 2;
            byte ^= (col & 7) << 4;
            bf16x8 b = *(const bf16x8*)((const char*)Wl + byte);
            acc[nf] = __builtin_amdgcn_mfma_f32_16x16x32_bf16(a8[ks], b, acc[nf], 0, 0, 0);
        }
    }

#pragma unroll
    for (int nf = 0; nf < 8; ++nf) {
#pragma unroll
        for (int j = 0; j < 4; ++j) {
            int row = r0 + (lane >> 4) * 4 + j;
            if (row < N)
                h1b[(long)row * HID + nf * 16 + (lane & 15)] = f2bf(acc[nf][j]);
        }
    }
}

// ---------------- agg1 (pull): agg[n] = sum h1b[src]  (bf16 gather, f32 accum) ----------
__global__ __launch_bounds__(256) void agg1_kernel(
    const int* __restrict__ row_ptr, const int* __restrict__ row_end,
    const int* __restrict__ csr_src, const unsigned* __restrict__ h1b2,  // [N][64] uint
    float* __restrict__ agg, int N) {
    int node = (blockIdx.x * 256 + threadIdx.x) >> 6;
    int lane = threadIdx.x & 63;
    if (node >= N) return;
    int e = row_ptr[node], end = row_end[node];
    float ax = 0.f, ay = 0.f;
    for (; e + 4 <= end; e += 4) {
        int s0 = csr_src[e], s1 = csr_src[e + 1], s2 = csr_src[e + 2], s3 = csr_src[e + 3];
        unsigned u0 = h1b2[(long)s0 * 64 + lane];
        unsigned u1 = h1b2[(long)s1 * 64 + lane];
        unsigned u2 = h1b2[(long)s2 * 64 + lane];
        unsigned u3 = h1b2[(long)s3 * 64 + lane];
        ax += __builtin_bit_cast(float, u0 << 16) + __builtin_bit_cast(float, u1 << 16)
            + __builtin_bit_cast(float, u2 << 16) + __builtin_bit_cast(float, u3 << 16);
        ay += __builtin_bit_cast(float, u0 & 0xffff0000u) + __builtin_bit_cast(float, u1 & 0xffff0000u)
            + __builtin_bit_cast(float, u2 & 0xffff0000u) + __builtin_bit_cast(float, u3 & 0xffff0000u);
    }
    for (; e < end; ++e) {
        unsigned u = h1b2[(long)csr_src[e] * 64 + lane];
        ax += __builtin_bit_cast(float, u << 16);
        ay += __builtin_bit_cast(float, u & 0xffff0000u);
    }
    float2 o; o.x = ax; o.y = ay;
    *(float2*)&agg[(long)node * HID + 2 * lane] = o;
}

// ---------------- GEMM2: h2b = bf16((relu(agg*rs_in+b1)*rs_out) @ W2) [N,128]@[128,40] --
__global__ __launch_bounds__(256) void gemm2_kernel(
    const float* __restrict__ agg1, const float* __restrict__ W2,
    const float* __restrict__ b1, const float* __restrict__ rs_in,
    const float* __restrict__ rs_out, unsigned short* __restrict__ h2b, int N) {
    __shared__ float xs[64][128];
    __shared__ float ws[128][NCLS];
    const int tx = threadIdx.x;
    const int row0 = blockIdx.x * 64;

    for (int idx = tx; idx < 128 * NCLS; idx += 256)
        ((float*)ws)[idx] = W2[idx];
#pragma unroll
    for (int j = 0; j < 32; ++j) {
        int idx = tx + 256 * j;
        int r = idx >> 7, k = idx & 127;
        int gr = row0 + r;
        float v = 0.f;
        if (gr < N)
            v = fmaxf(fmaf(agg1[(long)gr * HID + k], rs_in[gr], b1[k]), 0.f) * rs_out[gr];
        xs[r][k] = v;
    }
    __syncthreads();

    const int wv = tx >> 6, lane = tx & 63;
    if (lane < NCLS) {
        for (int rb = 0; rb < 16; rb += 4) {
            int r = wv * 16 + rb;
            float a0 = 0.f, a1 = 0.f, a2 = 0.f, a3 = 0.f;
            for (int k = 0; k < 128; k += 4) {
                float w0 = ws[k][lane], w1 = ws[k + 1][lane];
                float w2 = ws[k + 2][lane], w3 = ws[k + 3][lane];
                float4 x0 = *(const float4*)&xs[r    ][k];
                float4 x1 = *(const float4*)&xs[r + 1][k];
                float4 x2 = *(const float4*)&xs[r + 2][k];
                float4 x3 = *(const float4*)&xs[r + 3][k];
                a0 = fmaf(x0.x, w0, fmaf(x0.y, w1, fmaf(x0.z, w2, fmaf(x0.w, w3, a0))));
                a1 = fmaf(x1.x, w0, fmaf(x1.y, w1, fmaf(x1.z, w2, fmaf(x1.w, w3, a1))));
                a2 = fmaf(x2.x, w0, fmaf(x2.y, w1, fmaf(x2.z, w2, fmaf(x2.w, w3, a2))));
                a3 = fmaf(x3.x, w0, fmaf(x3.y, w1, fmaf(x3.z, w2, fmaf(x3.w, w3, a3))));
            }
            int gr = row0 + r;
            if (gr     < N) h2b[(long)gr * NCLS + lane] = f2bf(a0);
            if (gr + 1 < N) h2b[(long)(gr + 1) * NCLS + lane] = f2bf(a1);
            if (gr + 2 < N) h2b[(long)(gr + 2) * NCLS + lane] = f2bf(a2);
            if (gr + 3 < N) h2b[(long)(gr + 3) * NCLS + lane] = f2bf(a3);
        }
    }
}

// ---------------- agg2 (pull) + epilogue: thread per (node, col-pair) -------------------
__global__ __launch_bounds__(256) void agg2_kernel(
    const int* __restrict__ row_ptr, const int* __restrict__ row_end,
    const int* __restrict__ csr_src, const unsigned* __restrict__ h2b2,  // [N][20] uint
    const float* __restrict__ rs_in, const float* __restrict__ b2,
    float* __restrict__ out, int N) {
    int i = blockIdx.x * 256 + threadIdx.x;
    if (i >= N * 20) return;
    int node = i / 20;
    int cp   = i - node * 20;
    int e = row_ptr[node], end = row_end[node];
    float ax = 0.f, ay = 0.f;
    for (; e + 4 <= end; e += 4) {
        int s0 = csr_src[e], s1 = csr_src[e + 1], s2 = csr_src[e + 2], s3 = csr_src[e + 3];
        unsigned u0 = h2b2[(long)s0 * 20 + cp];
        unsigned u1 = h2b2[(long)s1 * 20 + cp];
        unsigned u2 = h2b2[(long)s2 * 20 + cp];
        unsigned u3 = h2b2[(long)s3 * 20 + cp];
        ax += __builtin_bit_cast(float, u0 << 16) + __builtin_bit_cast(float, u1 << 16)
            + __builtin_bit_cast(float, u2 << 16) + __builtin_bit_cast(float, u3 << 16);
        ay += __builtin_bit_cast(float, u0 & 0xffff0000u) + __builtin_bit_cast(float, u1 & 0xffff0000u)
            + __builtin_bit_cast(float, u2 & 0xffff0000u) + __builtin_bit_cast(float, u3 & 0xffff0000u);
    }
    for (; e < end; ++e) {
        unsigned u = h2b2[(long)csr_src[e] * 20 + cp];
        ax += __builtin_bit_cast(float, u << 16);
        ay += __builtin_bit_cast(float, u & 0xffff0000u);
    }
    float r = rs_in[node];
    float2 o;
    o.x = fmaf(ax, r, b2[2 * cp]);
    o.y = fmaf(ay, r, b2[2 * cp + 1]);
    *(float2*)&out[(long)node * NCLS + 2 * cp] = o;
}

extern "C" void kernel_launch(void* const* d_in, const int* in_sizes, int n_in,
                              void* d_out, int out_size, void* d_ws, size_t ws_size,
                              hipStream_t stream) {
    const float* x  = (const float*)d_in[0];
    const float* W1 = (const float*)d_in[1];
    const float* b1 = (const float*)d_in[2];
    const float* W2 = (const float*)d_in[3];
    const float* b2 = (const float*)d_in[4];
    const int*  src = (const int*)d_in[5];
    const int*  dst = (const int*)d_in[6];
    const int N = in_sizes[0] / IN_F;
    const int E = in_sizes[5];

    float* wsf      = (float*)d_ws;
    float* rs_out   = wsf;                         // N f
    float* rs_in    = wsf + N;                     // N f
    int*   cnt_out  = (int*)(wsf + 2 * (long)N);   // N i      (zeroed, contiguous w/ bktCnt)
    int*   bktCnt   = cnt_out + N;                 // MAXBKT i (zeroed)
    int*   bktBase  = bktCnt + MAXBKT;             // MAXBKT i
    int*   bktCursor= bktBase + MAXBKT;            // MAXBKT i
    int*   row_ptr  = bktCursor + MAXBKT;          // N+64 i
    int*   bin      = row_ptr + N + 64;            // E i
    int*   csr_src  = bin + E;                     // E i
    unsigned short* h1b = (unsigned short*)(csr_src + E);          // N*128 bf16
    float* agg1     = (float*)(h1b + (long)N * HID);               // N*128 f
    unsigned short* h2b = (unsigned short*)(agg1 + (long)N * HID); // N*40 bf16

    // zero cnt_out + bktCnt (contiguous)
    {
        int n4 = (N + MAXBKT) / 4;
        zero4_kernel<<<(n4 + 255) / 256, 256, 0, stream>>>((float4*)cnt_out, n4);
    }

    count_kernel<<<128, 256, 0, stream>>>(src, dst, cnt_out, bktCnt, E);
    bscan_kernel<<<1, 1024, 0, stream>>>(bktCnt, bktBase, bktCursor);
    rsout_kernel<<<(N + 255) / 256, 256, 0, stream>>>(cnt_out, rs_out, N);
    binA_kernel<<<(E + 255) / 256, 256, 0, stream>>>(src, dst, bktCursor, bin, E);
    passB_kernel<<<(N >> 6) + 1, 256, 0, stream>>>(bktBase, bin, csr_src, row_ptr, rs_in, N);

    gemm1_kernel<<<(N + 63) / 64, 256, 0, stream>>>(x, W1, rs_out, h1b, N);
    agg1_kernel<<<(N * 64 + 255) / 256, 256, 0, stream>>>(row_ptr, row_ptr + 1, csr_src,
                                                          (const unsigned*)h1b, agg1, N);
    gemm2_kernel<<<(N + 63) / 64, 256, 0, stream>>>(agg1, W2, b1, rs_in, rs_out, h2b, N);
    agg2_kernel<<<(N * 20 + 255) / 256, 256, 0, stream>>>(row_ptr, row_ptr + 1, csr_src,
                                                          (const unsigned*)h2b, rs_in, b2,
                                                          (float*)d_out, N);
}

// Round 7
// 728.600 us; speedup vs baseline: 1.4949x; 1.4949x over previous
//
#include <hip/hip_runtime.h>

#define IN_F 256
#define HID  128
#define NCLS 40
#define NBKT 256        // coarse buckets of 512 nodes: supports N <= 131072
#define BKTSH 9         // 512 nodes per bucket
#define CH 16384        // edges per binning chunk

typedef __attribute__((ext_vector_type(8))) short bf16x8;
typedef __attribute__((ext_vector_type(4))) float f32x4;

static __device__ __forceinline__ unsigned short f2bf(float f) {
    unsigned u = __builtin_bit_cast(unsigned, f);
    u += 0x7fffu + ((u >> 16) & 1u);   // round-to-nearest-even
    return (unsigned short)(u >> 16);
}

// ---------------- zero ----------------
__global__ void zero4_kernel(float4* __restrict__ p, int n4) {
    int i = blockIdx.x * blockDim.x + threadIdx.x;
    if (i < n4) p[i] = make_float4(0.f, 0.f, 0.f, 0.f);
}

// ---------------- count: LDS coarse-bucket histogram + global out-degree ----------------
__global__ __launch_bounds__(256) void count_kernel(
    const int* __restrict__ src, const int* __restrict__ dst,
    int* __restrict__ cnt_out, int* __restrict__ bktCnt, int E) {
    __shared__ int hist[NBKT];
    hist[threadIdx.x] = 0;
    __syncthreads();
    int stride = gridDim.x * 256;
    for (int i = blockIdx.x * 256 + threadIdx.x; i < E; i += stride) {
        atomicAdd(&cnt_out[src[i]], 1);
        atomicAdd(&hist[dst[i] >> BKTSH], 1);
    }
    __syncthreads();
    int c = hist[threadIdx.x];
    if (c) atomicAdd(&bktCnt[threadIdx.x], c);
}

// ---------------- bucket exclusive scan (one block, 256 entries) ----------------
__global__ __launch_bounds__(256) void bscan_kernel(const int* __restrict__ bktCnt,
                                                    int* __restrict__ bktBase,
                                                    int* __restrict__ bktCursor) {
    __shared__ int s[256];
    int t = threadIdx.x;
    int v = bktCnt[t];
    s[t] = v;
    __syncthreads();
    for (int off = 1; off < 256; off <<= 1) {
        int u = (t >= off) ? s[t - off] : 0;
        __syncthreads();
        s[t] += u;
        __syncthreads();
    }
    int excl = s[t] - v;
    bktBase[t] = excl;
    bktCursor[t] = excl;
    if (t == 255) bktBase[256] = s[t];   // total = E
}

__global__ void rsout_kernel(const int* __restrict__ cnt_out, float* __restrict__ rs_out, int N) {
    int i = blockIdx.x * blockDim.x + threadIdx.x;
    if (i < N) rs_out[i] = rsqrtf((float)max(cnt_out[i], 1));
}

// ---------------- binA: two-pass chunk -> dense per-bucket appends ----------------
__global__ __launch_bounds__(256) void binA_kernel(
    const int* __restrict__ src, const int* __restrict__ dst,
    int* __restrict__ bktCursor, int* __restrict__ bin, int E) {
    __shared__ int cnt[NBKT];
    __shared__ int ofs[NBKT];
    const int tx = threadIdx.x;
    const int be = blockIdx.x * CH;
    const int ee = min(be + CH, E);
    cnt[tx] = 0;
    __syncthreads();
    for (int i = be + tx; i < ee; i += 256)
        atomicAdd(&cnt[dst[i] >> BKTSH], 1);
    __syncthreads();
    int c = cnt[tx];
    ofs[tx] = c ? atomicAdd(&bktCursor[tx], c) : 0;   // bulk reservation
    cnt[tx] = 0;                                       // reuse as local cursor
    __syncthreads();
    for (int i = be + tx; i < ee; i += 256) {
        int d = dst[i];
        int b = d >> BKTSH;
        int l = atomicAdd(&cnt[b], 1);
        bin[ofs[b] + l] = ((d & 511) << 17) | src[i];  // src < 2^17
    }
}

// ---------------- passB: per-bucket (512 nodes) LDS counting sort ----------------
__global__ __launch_bounds__(256) void passB_kernel(
    const int* __restrict__ bktBase, const int* __restrict__ bin,
    int* __restrict__ csr_src, int* __restrict__ row_ptr, float* __restrict__ rs_in, int N) {
    __shared__ int cnt[512];
    __shared__ int cur[512];
    __shared__ int part[256];
    const int b = blockIdx.x;
    const int base = bktBase[b], end = bktBase[b + 1];
    const int tx = threadIdx.x;
    cnt[tx] = 0; cnt[tx + 256] = 0;
    __syncthreads();
    for (int i = base + tx; i < end; i += 256)
        atomicAdd(&cnt[bin[i] >> 17], 1);
    __syncthreads();
    // exclusive scan over 512 (2 entries/thread)
    int a0 = cnt[2 * tx], a1 = cnt[2 * tx + 1];
    part[tx] = a0 + a1;
    __syncthreads();
    for (int off = 1; off < 256; off <<= 1) {
        int v = (tx >= off) ? part[tx - off] : 0;
        __syncthreads();
        part[tx] += v;
        __syncthreads();
    }
    int excl = part[tx] - (a0 + a1);
    cur[2 * tx] = excl;
    cur[2 * tx + 1] = excl + a0;
    int idx = (b << BKTSH) + 2 * tx;
    row_ptr[idx]     = base + excl;
    row_ptr[idx + 1] = base + excl + a0;
    if (idx < N)     rs_in[idx]     = rsqrtf((float)max(a0, 1));
    if (idx + 1 < N) rs_in[idx + 1] = rsqrtf((float)max(a1, 1));
    __syncthreads();
    for (int i = base + tx; i < end; i += 256) {
        int v = bin[i];
        int nl = v >> 17;
        int p = atomicAdd(&cur[nl], 1);
        csr_src[base + p] = v & 0x1FFFF;
    }
}

// ---------------- GEMM1 (MFMA bf16): h1b = bf16((x*rs_out) @ W1)  [N,256]@[256,128] ------
__global__ __launch_bounds__(256) void gemm1_kernel(
    const float* __restrict__ x, const float* __restrict__ W1,
    const float* __restrict__ rs_out, unsigned short* __restrict__ h1b, int N) {
    __shared__ unsigned short Wl[32768];  // 64 KB

    const int tx = threadIdx.x;
#pragma unroll
    for (int e = 0; e < 32; ++e) {
        int base = (tx + 256 * e) * 4;
        float4 w = *(const float4*)&W1[base];
        int k = base >> 7;
        int c0 = base & 127;
        float wv[4] = {w.x, w.y, w.z, w.w};
#pragma unroll
        for (int q = 0; q < 4; ++q) {
            int col = c0 + q;
            int byte = col * 512 + k * 2;
            byte ^= (col & 7) << 4;
            Wl[byte >> 1] = f2bf(wv[q]);
        }
    }
    __syncthreads();

    const int wv_ = tx >> 6, lane = tx & 63;
    const int r0 = blockIdx.x * 64 + wv_ * 16;
    const int arow = r0 + (lane & 15);
    const int arow_c = min(arow, N - 1);
    const float rs = rs_out[arow_c];
    const long xbase = (long)arow_c * IN_F + (lane >> 4) * 8;

    bf16x8 a8[8];
#pragma unroll
    for (int ks = 0; ks < 8; ++ks) {
        float4 p0 = *(const float4*)&x[xbase + ks * 32];
        float4 p1 = *(const float4*)&x[xbase + ks * 32 + 4];
        bf16x8 a;
        a[0] = (short)f2bf(p0.x * rs); a[1] = (short)f2bf(p0.y * rs);
        a[2] = (short)f2bf(p0.z * rs); a[3] = (short)f2bf(p0.w * rs);
        a[4] = (short)f2bf(p1.x * rs); a[5] = (short)f2bf(p1.y * rs);
        a[6] = (short)f2bf(p1.z * rs); a[7] = (short)f2bf(p1.w * rs);
        a8[ks] = a;
    }

    f32x4 acc[8];
#pragma unroll
    for (int nf = 0; nf < 8; ++nf) acc[nf] = (f32x4){0.f, 0.f, 0.f, 0.f};

#pragma unroll
    for (int ks = 0; ks < 8; ++ks) {
#pragma unroll
        for (int nf = 0; nf < 8; ++nf) {
            int col = nf * 16 + (lane & 15);
            int kb  = ks * 32 + (lane >> 4) * 8;
            int byte = col * 512 + kb * 2;
            byte ^= (col & 7) << 4;
            bf16x8 b = *(const bf16x8*)((const char*)Wl + byte);
            acc[nf] = __builtin_amdgcn_mfma_f32_16x16x32_bf16(a8[ks], b, acc[nf], 0, 0, 0);
        }
    }

#pragma unroll
    for (int nf = 0; nf < 8; ++nf) {
#pragma unroll
        for (int j = 0; j < 4; ++j) {
            int row = r0 + (lane >> 4) * 4 + j;
            if (row < N)
                h1b[(long)row * HID + nf * 16 + (lane & 15)] = f2bf(acc[nf][j]);
        }
    }
}

// ---------------- agg1 (pull): agg[n] = sum h1b[src]  (bf16 gather, f32 accum) ----------
__global__ __launch_bounds__(256) void agg1_kernel(
    const int* __restrict__ row_ptr, const int* __restrict__ row_end,
    const int* __restrict__ csr_src, const unsigned* __restrict__ h1b2,  // [N][64] uint
    float* __restrict__ agg, int N) {
    int node = (blockIdx.x * 256 + threadIdx.x) >> 6;
    int lane = threadIdx.x & 63;
    if (node >= N) return;
    int e = row_ptr[node], end = row_end[node];
    float ax = 0.f, ay = 0.f;
    for (; e + 4 <= end; e += 4) {
        int s0 = csr_src[e], s1 = csr_src[e + 1], s2 = csr_src[e + 2], s3 = csr_src[e + 3];
        unsigned u0 = h1b2[(long)s0 * 64 + lane];
        unsigned u1 = h1b2[(long)s1 * 64 + lane];
        unsigned u2 = h1b2[(long)s2 * 64 + lane];
        unsigned u3 = h1b2[(long)s3 * 64 + lane];
        ax += __builtin_bit_cast(float, u0 << 16) + __builtin_bit_cast(float, u1 << 16)
            + __builtin_bit_cast(float, u2 << 16) + __builtin_bit_cast(float, u3 << 16);
        ay += __builtin_bit_cast(float, u0 & 0xffff0000u) + __builtin_bit_cast(float, u1 & 0xffff0000u)
            + __builtin_bit_cast(float, u2 & 0xffff0000u) + __builtin_bit_cast(float, u3 & 0xffff0000u);
    }
    for (; e < end; ++e) {
        unsigned u = h1b2[(long)csr_src[e] * 64 + lane];
        ax += __builtin_bit_cast(float, u << 16);
        ay += __builtin_bit_cast(float, u & 0xffff0000u);
    }
    float2 o; o.x = ax; o.y = ay;
    *(float2*)&agg[(long)node * HID + 2 * lane] = o;
}

// ---------------- GEMM2: h2b = bf16((relu(agg*rs_in+b1)*rs_out) @ W2) [N,128]@[128,40] --
__global__ __launch_bounds__(256) void gemm2_kernel(
    const float* __restrict__ agg1, const float* __restrict__ W2,
    const float* __restrict__ b1, const float* __restrict__ rs_in,
    const float* __restrict__ rs_out, unsigned short* __restrict__ h2b, int N) {
    __shared__ float xs[64][128];
    __shared__ float ws[128][NCLS];
    const int tx = threadIdx.x;
    const int row0 = blockIdx.x * 64;

    for (int idx = tx; idx < 128 * NCLS; idx += 256)
        ((float*)ws)[idx] = W2[idx];
#pragma unroll
    for (int j = 0; j < 32; ++j) {
        int idx = tx + 256 * j;
        int r = idx >> 7, k = idx & 127;
        int gr = row0 + r;
        float v = 0.f;
        if (gr < N)
            v = fmaxf(fmaf(agg1[(long)gr * HID + k], rs_in[gr], b1[k]), 0.f) * rs_out[gr];
        xs[r][k] = v;
    }
    __syncthreads();

    const int wv = tx >> 6, lane = tx & 63;
    if (lane < NCLS) {
        for (int rb = 0; rb < 16; rb += 4) {
            int r = wv * 16 + rb;
            float a0 = 0.f, a1 = 0.f, a2 = 0.f, a3 = 0.f;
            for (int k = 0; k < 128; k += 4) {
                float w0 = ws[k][lane], w1 = ws[k + 1][lane];
                float w2 = ws[k + 2][lane], w3 = ws[k + 3][lane];
                float4 x0 = *(const float4*)&xs[r    ][k];
                float4 x1 = *(const float4*)&xs[r + 1][k];
                float4 x2 = *(const float4*)&xs[r + 2][k];
                float4 x3 = *(const float4*)&xs[r + 3][k];
                a0 = fmaf(x0.x, w0, fmaf(x0.y, w1, fmaf(x0.z, w2, fmaf(x0.w, w3, a0))));
                a1 = fmaf(x1.x, w0, fmaf(x1.y, w1, fmaf(x1.z, w2, fmaf(x1.w, w3, a1))));
                a2 = fmaf(x2.x, w0, fmaf(x2.y, w1, fmaf(x2.z, w2, fmaf(x2.w, w3, a2))));
                a3 = fmaf(x3.x, w0, fmaf(x3.y, w1, fmaf(x3.z, w2, fmaf(x3.w, w3, a3))));
            }
            int gr = row0 + r;
            if (gr     < N) h2b[(long)gr * NCLS + lane] = f2bf(a0);
            if (gr + 1 < N) h2b[(long)(gr + 1) * NCLS + lane] = f2bf(a1);
            if (gr + 2 < N) h2b[(long)(gr + 2) * NCLS + lane] = f2bf(a2);
            if (gr + 3 < N) h2b[(long)(gr + 3) * NCLS + lane] = f2bf(a3);
        }
    }
}

// ---------------- agg2 (pull) + epilogue: thread per (node, col-pair) -------------------
__global__ __launch_bounds__(256) void agg2_kernel(
    const int* __restrict__ row_ptr, const int* __restrict__ row_end,
    const int* __restrict__ csr_src, const unsigned* __restrict__ h2b2,  // [N][20] uint
    const float* __restrict__ rs_in, const float* __restrict__ b2,
    float* __restrict__ out, int N) {
    int i = blockIdx.x * 256 + threadIdx.x;
    if (i >= N * 20) return;
    int node = i / 20;
    int cp   = i - node * 20;
    int e = row_ptr[node], end = row_end[node];
    float ax = 0.f, ay = 0.f;
    for (; e + 4 <= end; e += 4) {
        int s0 = csr_src[e], s1 = csr_src[e + 1], s2 = csr_src[e + 2], s3 = csr_src[e + 3];
        unsigned u0 = h2b2[(long)s0 * 20 + cp];
        unsigned u1 = h2b2[(long)s1 * 20 + cp];
        unsigned u2 = h2b2[(long)s2 * 20 + cp];
        unsigned u3 = h2b2[(long)s3 * 20 + cp];
        ax += __builtin_bit_cast(float, u0 << 16) + __builtin_bit_cast(float, u1 << 16)
            + __builtin_bit_cast(float, u2 << 16) + __builtin_bit_cast(float, u3 << 16);
        ay += __builtin_bit_cast(float, u0 & 0xffff0000u) + __builtin_bit_cast(float, u1 & 0xffff0000u)
            + __builtin_bit_cast(float, u2 & 0xffff0000u) + __builtin_bit_cast(float, u3 & 0xffff0000u);
    }
    for (; e < end; ++e) {
        unsigned u = h2b2[(long)csr_src[e] * 20 + cp];
        ax += __builtin_bit_cast(float, u << 16);
        ay += __builtin_bit_cast(float, u & 0xffff0000u);
    }
    float r = rs_in[node];
    float2 o;
    o.x = fmaf(ax, r, b2[2 * cp]);
    o.y = fmaf(ay, r, b2[2 * cp + 1]);
    *(float2*)&out[(long)node * NCLS + 2 * cp] = o;
}

extern "C" void kernel_launch(void* const* d_in, const int* in_sizes, int n_in,
                              void* d_out, int out_size, void* d_ws, size_t ws_size,
                              hipStream_t stream) {
    const float* x  = (const float*)d_in[0];
    const float* W1 = (const float*)d_in[1];
    const float* b1 = (const float*)d_in[2];
    const float* W2 = (const float*)d_in[3];
    const float* b2 = (const float*)d_in[4];
    const int*  src = (const int*)d_in[5];
    const int*  dst = (const int*)d_in[6];
    const int N = in_sizes[0] / IN_F;
    const int E = in_sizes[5];

    float* wsf      = (float*)d_ws;
    float* rs_out   = wsf;                         // N f
    float* rs_in    = wsf + N;                     // N f
    int*   cnt_out  = (int*)(wsf + 2 * (long)N);   // N i   (zeroed, contiguous w/ bktCnt)
    int*   bktCnt   = cnt_out + N;                 // NBKT i (zeroed)
    int*   bktBase  = bktCnt + NBKT;               // NBKT+4 i
    int*   bktCursor= bktBase + NBKT + 4;          // NBKT i
    int*   row_ptr  = bktCursor + NBKT;            // N+1024 i
    int*   bin      = row_ptr + N + 1024;          // E i
    int*   csr_src  = bin + E;                     // E i
    unsigned short* h1b = (unsigned short*)(csr_src + E);          // N*128 bf16
    float* agg1     = (float*)(h1b + (long)N * HID);               // N*128 f
    unsigned short* h2b = (unsigned short*)(agg1 + (long)N * HID); // N*40 bf16

    // zero cnt_out + bktCnt (contiguous)
    {
        int n4 = (N + NBKT) / 4;
        zero4_kernel<<<(n4 + 255) / 256, 256, 0, stream>>>((float4*)cnt_out, n4);
    }

    count_kernel<<<256, 256, 0, stream>>>(src, dst, cnt_out, bktCnt, E);
    bscan_kernel<<<1, 256, 0, stream>>>(bktCnt, bktBase, bktCursor);
    rsout_kernel<<<(N + 255) / 256, 256, 0, stream>>>(cnt_out, rs_out, N);
    binA_kernel<<<(E + CH - 1) / CH, 256, 0, stream>>>(src, dst, bktCursor, bin, E);
    passB_kernel<<<(N + 511) / 512, 256, 0, stream>>>(bktBase, bin, csr_src, row_ptr, rs_in, N);

    gemm1_kernel<<<(N + 63) / 64, 256, 0, stream>>>(x, W1, rs_out, h1b, N);
    agg1_kernel<<<(N * 64 + 255) / 256, 256, 0, stream>>>(row_ptr, row_ptr + 1, csr_src,
                                                          (const unsigned*)h1b, agg1, N);
    gemm2_kernel<<<(N + 63) / 64, 256, 0, stream>>>(agg1, W2, b1, rs_in, rs_out, h2b, N);
    agg2_kernel<<<(N * 20 + 255) / 256, 256, 0, stream>>>(row_ptr, row_ptr + 1, csr_src,
                                                          (const unsigned*)h2b, rs_in, b2,
                                                          (float*)d_out, N);
}

// Round 8
// 544.058 us; speedup vs baseline: 2.0020x; 1.3392x over previous
//
#include <hip/hip_runtime.h>

#define IN_F 256
#define HID  128
#define NCLS 40
#define NBKT 256        // coarse buckets of 512 nodes: supports N <= 131072
#define BKTSH 9         // 512 nodes per bucket
#define CH 16384        // edges per binning chunk

typedef __attribute__((ext_vector_type(8))) short bf16x8;
typedef __attribute__((ext_vector_type(4))) float f32x4;

static __device__ __forceinline__ unsigned short f2bf(float f) {
    unsigned u = __builtin_bit_cast(unsigned, f);
    u += 0x7fffu + ((u >> 16) & 1u);   // round-to-nearest-even
    return (unsigned short)(u >> 16);
}

// ---------------- zero ----------------
__global__ void zero4_kernel(float4* __restrict__ p, int n4) {
    int i = blockIdx.x * blockDim.x + threadIdx.x;
    if (i < n4) p[i] = make_float4(0.f, 0.f, 0.f, 0.f);
}

// ---------------- count: LDS coarse-bucket histogram + global out-degree ----------------
__global__ __launch_bounds__(256) void count_kernel(
    const int* __restrict__ src, const int* __restrict__ dst,
    int* __restrict__ cnt_out, int* __restrict__ bktCnt, int E) {
    __shared__ int hist[NBKT];
    hist[threadIdx.x] = 0;
    __syncthreads();
    int stride = gridDim.x * 256;
    for (int i = blockIdx.x * 256 + threadIdx.x; i < E; i += stride) {
        atomicAdd(&cnt_out[src[i]], 1);
        atomicAdd(&hist[dst[i] >> BKTSH], 1);
    }
    __syncthreads();
    int c = hist[threadIdx.x];
    if (c) atomicAdd(&bktCnt[threadIdx.x], c);
}

// ---------------- bucket exclusive scan (one block, 256 entries) ----------------
__global__ __launch_bounds__(256) void bscan_kernel(const int* __restrict__ bktCnt,
                                                    int* __restrict__ bktBase,
                                                    int* __restrict__ bktCursor) {
    __shared__ int s[256];
    int t = threadIdx.x;
    int v = bktCnt[t];
    s[t] = v;
    __syncthreads();
    for (int off = 1; off < 256; off <<= 1) {
        int u = (t >= off) ? s[t - off] : 0;
        __syncthreads();
        s[t] += u;
        __syncthreads();
    }
    int excl = s[t] - v;
    bktBase[t] = excl;
    bktCursor[t] = excl;
    if (t == 255) bktBase[256] = s[t];   // total = E
}

__global__ void rsout_kernel(const int* __restrict__ cnt_out, float* __restrict__ rs_out, int N) {
    int i = blockIdx.x * blockDim.x + threadIdx.x;
    if (i < N) rs_out[i] = rsqrtf((float)max(cnt_out[i], 1));
}

// ---------------- binA: two-pass chunk -> dense per-bucket appends ----------------
__global__ __launch_bounds__(256) void binA_kernel(
    const int* __restrict__ src, const int* __restrict__ dst,
    int* __restrict__ bktCursor, int* __restrict__ bin, int E) {
    __shared__ int cnt[NBKT];
    __shared__ int ofs[NBKT];
    const int tx = threadIdx.x;
    const int be = blockIdx.x * CH;
    const int ee = min(be + CH, E);
    cnt[tx] = 0;
    __syncthreads();
    for (int i = be + tx; i < ee; i += 256)
        atomicAdd(&cnt[dst[i] >> BKTSH], 1);
    __syncthreads();
    int c = cnt[tx];
    ofs[tx] = c ? atomicAdd(&bktCursor[tx], c) : 0;   // bulk reservation
    cnt[tx] = 0;                                       // reuse as local cursor
    __syncthreads();
    for (int i = be + tx; i < ee; i += 256) {
        int d = dst[i];
        int b = d >> BKTSH;
        int l = atomicAdd(&cnt[b], 1);
        bin[ofs[b] + l] = ((d & 511) << 17) | src[i];  // src < 2^17
    }
}

// ---------------- passB: per-bucket (512 nodes) LDS counting sort ----------------
__global__ __launch_bounds__(256) void passB_kernel(
    const int* __restrict__ bktBase, const int* __restrict__ bin,
    int* __restrict__ csr_src, int* __restrict__ row_ptr, float* __restrict__ rs_in, int N) {
    __shared__ int cnt[512];
    __shared__ int cur[512];
    __shared__ int part[256];
    const int b = blockIdx.x;
    const int base = bktBase[b], end = bktBase[b + 1];
    const int tx = threadIdx.x;
    cnt[tx] = 0; cnt[tx + 256] = 0;
    __syncthreads();
    for (int i = base + tx; i < end; i += 256)
        atomicAdd(&cnt[bin[i] >> 17], 1);
    __syncthreads();
    // exclusive scan over 512 (2 entries/thread)
    int a0 = cnt[2 * tx], a1 = cnt[2 * tx + 1];
    part[tx] = a0 + a1;
    __syncthreads();
    for (int off = 1; off < 256; off <<= 1) {
        int v = (tx >= off) ? part[tx - off] : 0;
        __syncthreads();
        part[tx] += v;
        __syncthreads();
    }
    int excl = part[tx] - (a0 + a1);
    cur[2 * tx] = excl;
    cur[2 * tx + 1] = excl + a0;
    int idx = (b << BKTSH) + 2 * tx;
    row_ptr[idx]     = base + excl;
    row_ptr[idx + 1] = base + excl + a0;
    if (idx < N)     rs_in[idx]     = rsqrtf((float)max(a0, 1));
    if (idx + 1 < N) rs_in[idx + 1] = rsqrtf((float)max(a1, 1));
    __syncthreads();
    for (int i = base + tx; i < end; i += 256) {
        int v = bin[i];
        int nl = v >> 17;
        int p = atomicAdd(&cur[nl], 1);
        csr_src[base + p] = v & 0x1FFFF;
    }
}

// ---------------- GEMM1 (MFMA bf16): h1b = bf16((x*rs_out) @ W1)  [N,256]@[256,128] ------
__global__ __launch_bounds__(256) void gemm1_kernel(
    const float* __restrict__ x, const float* __restrict__ W1,
    const float* __restrict__ rs_out, unsigned short* __restrict__ h1b, int N) {
    __shared__ unsigned short Wl[32768];  // 64 KB

    const int tx = threadIdx.x;
#pragma unroll
    for (int e = 0; e < 32; ++e) {
        int base = (tx + 256 * e) * 4;
        float4 w = *(const float4*)&W1[base];
        int k = base >> 7;
        int c0 = base & 127;
        float wv[4] = {w.x, w.y, w.z, w.w};
#pragma unroll
        for (int q = 0; q < 4; ++q) {
            int col = c0 + q;
            int byte = col * 512 + k * 2;
            byte ^= (col & 7) << 4;
            Wl[byte >> 1] = f2bf(wv[q]);
        }
    }
    __syncthreads();

    const int wv_ = tx >> 6, lane = tx & 63;
    const int r0 = blockIdx.x * 64 + wv_ * 16;
    const int arow = r0 + (lane & 15);
    const int arow_c = min(arow, N - 1);
    const float rs = rs_out[arow_c];
    const long xbase = (long)arow_c * IN_F + (lane >> 4) * 8;

    bf16x8 a8[8];
#pragma unroll
    for (int ks = 0; ks < 8; ++ks) {
        float4 p0 = *(const float4*)&x[xbase + ks * 32];
        float4 p1 = *(const float4*)&x[xbase + ks * 32 + 4];
        bf16x8 a;
        a[0] = (short)f2bf(p0.x * rs); a[1] = (short)f2bf(p0.y * rs);
        a[2] = (short)f2bf(p0.z * rs); a[3] = (short)f2bf(p0.w * rs);
        a[4] = (short)f2bf(p1.x * rs); a[5] = (short)f2bf(p1.y * rs);
        a[6] = (short)f2bf(p1.z * rs); a[7] = (short)f2bf(p1.w * rs);
        a8[ks] = a;
    }

    f32x4 acc[8];
#pragma unroll
    for (int nf = 0; nf < 8; ++nf) acc[nf] = (f32x4){0.f, 0.f, 0.f, 0.f};

#pragma unroll
    for (int ks = 0; ks < 8; ++ks) {
#pragma unroll
        for (int nf = 0; nf < 8; ++nf) {
            int col = nf * 16 + (lane & 15);
            int kb  = ks * 32 + (lane >> 4) * 8;
            int byte = col * 512 + kb * 2;
            byte ^= (col & 7) << 4;
            bf16x8 b = *(const bf16x8*)((const char*)Wl + byte);
            acc[nf] = __builtin_amdgcn_mfma_f32_16x16x32_bf16(a8[ks], b, acc[nf], 0, 0, 0);
        }
    }

#pragma unroll
    for (int nf = 0; nf < 8; ++nf) {
#pragma unroll
        for (int j = 0; j < 4; ++j) {
            int row = r0 + (lane >> 4) * 4 + j;
            if (row < N)
                h1b[(long)row * HID + nf * 16 + (lane & 15)] = f2bf(acc[nf][j]);
        }
    }
}

// ---------------- agg1 (pull): agg[n] = sum h1b[src]  (bf16 gather, f32 accum) ----------
__global__ __launch_bounds__(256) void agg1_kernel(
    const int* __restrict__ row_ptr, const int* __restrict__ row_end,
    const int* __restrict__ csr_src, const unsigned* __restrict__ h1b2,  // [N][64] uint
    float* __restrict__ agg, int N) {
    int node = (blockIdx.x * 256 + threadIdx.x) >> 6;
    int lane = threadIdx.x & 63;
    if (node >= N) return;
    int e = row_ptr[node], end = row_end[node];
    float ax = 0.f, ay = 0.f;
    for (; e + 4 <= end; e += 4) {
        int s0 = csr_src[e], s1 = csr_src[e + 1], s2 = csr_src[e + 2], s3 = csr_src[e + 3];
        unsigned u0 = h1b2[(long)s0 * 64 + lane];
        unsigned u1 = h1b2[(long)s1 * 64 + lane];
        unsigned u2 = h1b2[(long)s2 * 64 + lane];
        unsigned u3 = h1b2[(long)s3 * 64 + lane];
        ax += __builtin_bit_cast(float, u0 << 16) + __builtin_bit_cast(float, u1 << 16)
            + __builtin_bit_cast(float, u2 << 16) + __builtin_bit_cast(float, u3 << 16);
        ay += __builtin_bit_cast(float, u0 & 0xffff0000u) + __builtin_bit_cast(float, u1 & 0xffff0000u)
            + __builtin_bit_cast(float, u2 & 0xffff0000u) + __builtin_bit_cast(float, u3 & 0xffff0000u);
    }
    for (; e < end; ++e) {
        unsigned u = h1b2[(long)csr_src[e] * 64 + lane];
        ax += __builtin_bit_cast(float, u << 16);
        ay += __builtin_bit_cast(float, u & 0xffff0000u);
    }
    float2 o; o.x = ax; o.y = ay;
    *(float2*)&agg[(long)node * HID + 2 * lane] = o;
}

// -------- GEMM2 (MFMA bf16): h2b = bf16((relu(agg*rs_in+b1)*rs_out) @ W2) [N,128]@[128,40]
// W2 staged in LDS col-major [48 cols][128 k] bf16, swizzled; cols 40..47 zero.
__global__ __launch_bounds__(256) void gemm2_kernel(
    const float* __restrict__ agg1, const float* __restrict__ W2,
    const float* __restrict__ b1, const float* __restrict__ rs_in,
    const float* __restrict__ rs_out, unsigned short* __restrict__ h2b, int N) {
    __shared__ unsigned short Wl[48 * 128];  // 12 KB

    const int tx = threadIdx.x;
    for (int idx = tx; idx < 48 * 128; idx += 256) Wl[idx] = 0;
    __syncthreads();
    for (int idx = tx; idx < 128 * NCLS; idx += 256) {
        int k = idx / NCLS, c = idx - k * NCLS;
        int byte = c * 256 + k * 2;
        byte ^= (c & 7) << 4;
        Wl[byte >> 1] = f2bf(W2[idx]);
    }
    __syncthreads();

    const int wv_ = tx >> 6, lane = tx & 63;
    const int r0 = blockIdx.x * 64 + wv_ * 16;
    const int arow = r0 + (lane & 15);
    const int arow_c = min(arow, N - 1);
    const float ri = rs_in[arow_c];
    const float ro = rs_out[arow_c];
    const int k0 = (lane >> 4) * 8;
    const long abase = (long)arow_c * HID + k0;

    // A fragments: relu(agg*rs_in + b1)*rs_out -> bf16, 4 k-steps x 8
    bf16x8 a8[4];
#pragma unroll
    for (int ks = 0; ks < 4; ++ks) {
        float4 p0 = *(const float4*)&agg1[abase + ks * 32];
        float4 p1 = *(const float4*)&agg1[abase + ks * 32 + 4];
        float4 c0 = *(const float4*)&b1[k0 + ks * 32];
        float4 c1 = *(const float4*)&b1[k0 + ks * 32 + 4];
        bf16x8 a;
        a[0] = (short)f2bf(fmaxf(fmaf(p0.x, ri, c0.x), 0.f) * ro);
        a[1] = (short)f2bf(fmaxf(fmaf(p0.y, ri, c0.y), 0.f) * ro);
        a[2] = (short)f2bf(fmaxf(fmaf(p0.z, ri, c0.z), 0.f) * ro);
        a[3] = (short)f2bf(fmaxf(fmaf(p0.w, ri, c0.w), 0.f) * ro);
        a[4] = (short)f2bf(fmaxf(fmaf(p1.x, ri, c1.x), 0.f) * ro);
        a[5] = (short)f2bf(fmaxf(fmaf(p1.y, ri, c1.y), 0.f) * ro);
        a[6] = (short)f2bf(fmaxf(fmaf(p1.z, ri, c1.z), 0.f) * ro);
        a[7] = (short)f2bf(fmaxf(fmaf(p1.w, ri, c1.w), 0.f) * ro);
        a8[ks] = a;
    }

    f32x4 acc[3];
#pragma unroll
    for (int nf = 0; nf < 3; ++nf) acc[nf] = (f32x4){0.f, 0.f, 0.f, 0.f};

#pragma unroll
    for (int ks = 0; ks < 4; ++ks) {
#pragma unroll
        for (int nf = 0; nf < 3; ++nf) {
            int col = nf * 16 + (lane & 15);
            int kb  = ks * 32 + k0;
            int byte = col * 256 + kb * 2;
            byte ^= (col & 7) << 4;
            bf16x8 b = *(const bf16x8*)((const char*)Wl + byte);
            acc[nf] = __builtin_amdgcn_mfma_f32_16x16x32_bf16(a8[ks], b, acc[nf], 0, 0, 0);
        }
    }

#pragma unroll
    for (int nf = 0; nf < 3; ++nf) {
        int col = nf * 16 + (lane & 15);
        if (col < NCLS) {
#pragma unroll
            for (int j = 0; j < 4; ++j) {
                int row = r0 + (lane >> 4) * 4 + j;
                if (row < N)
                    h2b[(long)row * NCLS + col] = f2bf(acc[nf][j]);
            }
        }
    }
}

// ---------------- agg2 (pull) + epilogue: thread per (node, col-pair) -------------------
__global__ __launch_bounds__(256) void agg2_kernel(
    const int* __restrict__ row_ptr, const int* __restrict__ row_end,
    const int* __restrict__ csr_src, const unsigned* __restrict__ h2b2,  // [N][20] uint
    const float* __restrict__ rs_in, const float* __restrict__ b2,
    float* __restrict__ out, int N) {
    int i = blockIdx.x * 256 + threadIdx.x;
    if (i >= N * 20) return;
    int node = i / 20;
    int cp   = i - node * 20;
    int e = row_ptr[node], end = row_end[node];
    float ax = 0.f, ay = 0.f;
    for (; e + 4 <= end; e += 4) {
        int s0 = csr_src[e], s1 = csr_src[e + 1], s2 = csr_src[e + 2], s3 = csr_src[e + 3];
        unsigned u0 = h2b2[(long)s0 * 20 + cp];
        unsigned u1 = h2b2[(long)s1 * 20 + cp];
        unsigned u2 = h2b2[(long)s2 * 20 + cp];
        unsigned u3 = h2b2[(long)s3 * 20 + cp];
        ax += __builtin_bit_cast(float, u0 << 16) + __builtin_bit_cast(float, u1 << 16)
            + __builtin_bit_cast(float, u2 << 16) + __builtin_bit_cast(float, u3 << 16);
        ay += __builtin_bit_cast(float, u0 & 0xffff0000u) + __builtin_bit_cast(float, u1 & 0xffff0000u)
            + __builtin_bit_cast(float, u2 & 0xffff0000u) + __builtin_bit_cast(float, u3 & 0xffff0000u);
    }
    for (; e < end; ++e) {
        unsigned u = h2b2[(long)csr_src[e] * 20 + cp];
        ax += __builtin_bit_cast(float, u << 16);
        ay += __builtin_bit_cast(float, u & 0xffff0000u);
    }
    float r = rs_in[node];
    float2 o;
    o.x = fmaf(ax, r, b2[2 * cp]);
    o.y = fmaf(ay, r, b2[2 * cp + 1]);
    *(float2*)&out[(long)node * NCLS + 2 * cp] = o;
}

extern "C" void kernel_launch(void* const* d_in, const int* in_sizes, int n_in,
                              void* d_out, int out_size, void* d_ws, size_t ws_size,
                              hipStream_t stream) {
    const float* x  = (const float*)d_in[0];
    const float* W1 = (const float*)d_in[1];
    const float* b1 = (const float*)d_in[2];
    const float* W2 = (const float*)d_in[3];
    const float* b2 = (const float*)d_in[4];
    const int*  src = (const int*)d_in[5];
    const int*  dst = (const int*)d_in[6];
    const int N = in_sizes[0] / IN_F;
    const int E = in_sizes[5];

    float* wsf      = (float*)d_ws;
    float* rs_out   = wsf;                         // N f
    float* rs_in    = wsf + N;                     // N f
    int*   cnt_out  = (int*)(wsf + 2 * (long)N);   // N i   (zeroed, contiguous w/ bktCnt)
    int*   bktCnt   = cnt_out + N;                 // NBKT i (zeroed)
    int*   bktBase  = bktCnt + NBKT;               // NBKT+4 i
    int*   bktCursor= bktBase + NBKT + 4;          // NBKT i
    int*   row_ptr  = bktCursor + NBKT;            // N+1024 i
    int*   bin      = row_ptr + N + 1024;          // E i
    int*   csr_src  = bin + E;                     // E i
    unsigned short* h1b = (unsigned short*)(csr_src + E);          // N*128 bf16
    float* agg1     = (float*)(h1b + (long)N * HID);               // N*128 f
    unsigned short* h2b = (unsigned short*)(agg1 + (long)N * HID); // N*40 bf16

    // zero cnt_out + bktCnt (contiguous)
    {
        int n4 = (N + NBKT) / 4;
        zero4_kernel<<<(n4 + 255) / 256, 256, 0, stream>>>((float4*)cnt_out, n4);
    }

    count_kernel<<<256, 256, 0, stream>>>(src, dst, cnt_out, bktCnt, E);
    bscan_kernel<<<1, 256, 0, stream>>>(bktCnt, bktBase, bktCursor);
    rsout_kernel<<<(N + 255) / 256, 256, 0, stream>>>(cnt_out, rs_out, N);
    binA_kernel<<<(E + CH - 1) / CH, 256, 0, stream>>>(src, dst, bktCursor, bin, E);
    passB_kernel<<<(N + 511) / 512, 256, 0, stream>>>(bktBase, bin, csr_src, row_ptr, rs_in, N);

    gemm1_kernel<<<(N + 63) / 64, 256, 0, stream>>>(x, W1, rs_out, h1b, N);
    agg1_kernel<<<(N * 64 + 255) / 256, 256, 0, stream>>>(row_ptr, row_ptr + 1, csr_src,
                                                          (const unsigned*)h1b, agg1, N);
    gemm2_kernel<<<(N + 63) / 64, 256, 0, stream>>>(agg1, W2, b1, rs_in, rs_out, h2b, N);
    agg2_kernel<<<(N * 20 + 255) / 256, 256, 0, stream>>>(row_ptr, row_ptr + 1, csr_src,
                                                          (const unsigned*)h2b, rs_in, b2,
                                                          (float*)d_out, N);
}